// Round 6
// baseline (7349.264 us; speedup 1.0000x reference)
//
#include <hip/hip_runtime.h>
#include <stdint.h>

// ============================================================================
// Qnet: GRU(IN=4096,H=1024) over W=256 steps, B=32, + VAE head (D=Z=100) + PNF
// 4 launches: k_probe / k_state_init / k_gemm_gi / k_recur (persistent 65
// blocks, 1 grid barrier per timestep).
// History:
//   r3 7666us: leader-only release/acquire barrier. 27us/step.
//   r4 10447us: fence-free + PER-ELEMENT sc1 h path. REGRESSED (latency chain).
//   r5 5306us: fence-free + bulk 64KB sc1 gather into LDS. 18us/step.
//       Post-mortem: FETCH 173MB identical r3/r4/r5 => it's g_gi line
//       over-fetch, NOT maintenance refetch. LDS_BANK_CONFLICT 2M->15M from
//       hs stride-2064 fragment reads (8-way). Remaining pole = per-step
//       65x64KB uncached sc1 gather (MALL round-trips).
//   r6 (this): SLOT-ROTATED h: g_hs[257][32][1024] bf16 (16.8MB). Step i
//       reads slot i with PLAIN cached wide loads (fresh lines each step ->
//       compulsory miss -> MALL -> always-current; sc1 stores don't allocate
//       in L2, dispatch-start invalidates cover cross-launch reuse), writes
//       slot i+1 with sc1 device-scope stores (1KB/block). LDS h-staging
//       deleted (bank conflicts back to baseline). Barrier stays relaxed,
//       fence-free.
// ============================================================================

#define MFMA16 __builtin_amdgcn_mfma_f32_16x16x32_bf16

using f32x4  = __attribute__((ext_vector_type(4))) float;
using bf16x8 = __attribute__((ext_vector_type(8))) short;

static constexpr int NB_MM  = 64;
static constexpr int NB_ALL = 65;
static constexpr int TPB    = 1024;
static constexpr int WSTEPS = 256;

// ---- module-global scratch (~67 MB; 51 MB scale proven, 149 MB known-bad) ----
__device__ __align__(256) unsigned short g_gi[8192u * 3072u];     // 50.33 MB
__device__ __align__(256) unsigned short g_hs[257u * 32u * 1024u];// 16.84 MB
__device__ __align__(256) unsigned       g_bar[64];
__device__ unsigned g_flag;                                       // 1=f32 io

__device__ __forceinline__ float bf2f(unsigned short v){
  unsigned u = ((unsigned)v) << 16;
  return __builtin_bit_cast(float, u);
}
__device__ __forceinline__ unsigned short f2bf(float f){
  unsigned u = __builtin_bit_cast(unsigned, f);
  u += 0x7FFFu + ((u >> 16) & 1u);          // RNE
  return (unsigned short)(u >> 16);
}
__device__ __forceinline__ float ldin(const void* p, size_t i){
  return g_flag ? ((const float*)p)[i] : bf2f(((const unsigned short*)p)[i]);
}
__device__ __forceinline__ unsigned short ldbf(const void* p, size_t i){
  return g_flag ? f2bf(((const float*)p)[i]) : ((const unsigned short*)p)[i];
}
__device__ __forceinline__ void stout(void* p, size_t i, float v){
  if (g_flag) ((float*)p)[i] = v;
  else        ((unsigned short*)p)[i] = f2bf(v);
}
// 16 consecutive elements -> 16 bf16 (two uint4), vectorized in either dtype
__device__ __forceinline__ void ld16(const void* p, size_t idx,
                                     uint4* lo, uint4* hi){
  if (g_flag){
    const float* f = (const float*)p + idx;
    float4 a = *(const float4*)(f);
    float4 b = *(const float4*)(f + 4);
    float4 c = *(const float4*)(f + 8);
    float4 d = *(const float4*)(f + 12);
    unsigned short s[16];
    s[0]=f2bf(a.x); s[1]=f2bf(a.y); s[2]=f2bf(a.z); s[3]=f2bf(a.w);
    s[4]=f2bf(b.x); s[5]=f2bf(b.y); s[6]=f2bf(b.z); s[7]=f2bf(b.w);
    s[8]=f2bf(c.x); s[9]=f2bf(c.y); s[10]=f2bf(c.z); s[11]=f2bf(c.w);
    s[12]=f2bf(d.x); s[13]=f2bf(d.y); s[14]=f2bf(d.z); s[15]=f2bf(d.w);
    *lo = *(uint4*)s; *hi = *(uint4*)(s + 8);
  } else {
    const unsigned short* q = (const unsigned short*)p + idx;
    *lo = *(const uint4*)q; *hi = *(const uint4*)(q + 8);
  }
}
__device__ __forceinline__ float sigm(float x){ return 1.f / (1.f + __expf(-x)); }
__device__ __forceinline__ float sane(float x, float lim){   // tripwire clamp
  return fminf(fmaxf(x, -lim), lim);
}

// ---------------------------------------------------------------------------
__global__ void k_probe(const void* noise){
  if (threadIdx.x == 0 && blockIdx.x == 0){
    const unsigned* w = (const unsigned*)noise;
    unsigned f = 0;
    for (int k = 0; k < 16; ++k)
      if ((w[k] & 0xFFFFu) > 0x3F80u) f = 1u;
    g_flag = f;
  }
}

// zero g_hs slot 0 (16384 dw) | g_bar (64 dw)
__global__ void k_state_init(){
  int i = blockIdx.x * blockDim.x + threadIdx.x;
  if (i < 16384) ((unsigned*)g_hs)[i] = 0u;
  else if (i < 16448) g_bar[i - 16384] = 0u;
}

// ---------------------------------------------------------------------------
// gi = x @ W_ih^T + b_ih.  M=8192, N=3072, K=4096. 128x128 tile, BK=32.
__global__ __launch_bounds__(256) void k_gemm_gi(
    const void* __restrict__ x,
    const void* __restrict__ Wih,
    const void* __restrict__ bih)
{
  __shared__ unsigned short As[128 * 40];
  __shared__ unsigned short Bs[128 * 40];
  const int tm = blockIdx.x & 63;
  const int tn = blockIdx.x >> 6;
  const int m0 = tm * 128, n0 = tn * 128;
  const int t  = threadIdx.x;
  const int wave = t >> 6, lane = t & 63;
  const int wm = wave & 1, wn = wave >> 1;
  const int ln = lane & 15, kg = lane >> 4;

  const int srow = t >> 1;
  const int skc  = (t & 1) * 16;
  const int m  = m0 + srow;
  const int bb = m & 31, ww = m >> 5;            // x is [B=32][W=256][4096]
  const size_t aoff = ((size_t)(bb * 256 + ww)) * 4096 + skc;
  const size_t boff = ((size_t)(n0 + srow)) * 4096 + skc;
  unsigned short* asl = &As[srow * 40 + skc];
  unsigned short* bsl = &Bs[srow * 40 + skc];

  f32x4 acc[4][4];
#pragma unroll
  for (int i = 0; i < 4; ++i)
#pragma unroll
    for (int j = 0; j < 4; ++j) acc[i][j] = (f32x4){0.f, 0.f, 0.f, 0.f};

  uint4 av, av2, bv, bv2;
  ld16(x,   aoff, &av, &av2);
  ld16(Wih, boff, &bv, &bv2);

  for (int k0 = 0; k0 < 4096; k0 += 32){
    __syncthreads();
    *(uint4*)asl = av;  *(uint4*)(asl + 8) = av2;
    *(uint4*)bsl = bv;  *(uint4*)(bsl + 8) = bv2;
    __syncthreads();
    if (k0 + 32 < 4096){
      ld16(x,   aoff + k0 + 32, &av, &av2);
      ld16(Wih, boff + k0 + 32, &bv, &bv2);
    }
    bf16x8 af[4], bfv[4];
#pragma unroll
    for (int mt = 0; mt < 4; ++mt)
      af[mt] = *(const bf16x8*)&As[(wm * 64 + mt * 16 + ln) * 40 + kg * 8];
#pragma unroll
    for (int nt = 0; nt < 4; ++nt)
      bfv[nt] = *(const bf16x8*)&Bs[(wn * 64 + nt * 16 + ln) * 40 + kg * 8];
#pragma unroll
    for (int mt = 0; mt < 4; ++mt)
#pragma unroll
      for (int nt = 0; nt < 4; ++nt)
        acc[mt][nt] = MFMA16(af[mt], bfv[nt], acc[mt][nt], 0, 0, 0);
  }

#pragma unroll
  for (int nt = 0; nt < 4; ++nt){
    const int gc = n0 + wn * 64 + nt * 16 + ln;
    const float bias = ldin(bih, gc);
#pragma unroll
    for (int mt = 0; mt < 4; ++mt){
      const int rb = m0 + wm * 64 + mt * 16 + kg * 4;
#pragma unroll
      for (int r = 0; r < 4; ++r)
        g_gi[(size_t)(rb + r) * 3072 + gc] = f2bf(acc[mt][nt][r] + bias);
    }
  }
}

// ---------------------------------------------------------------------------
struct P2Args {
  const void* Whh;   // [3072][1024]
  const void* bhh;   // [3072]
  const void* Wd;    // [100][1124]  (cols 0..99 = z, 100..1123 = h)
  const void* bd;
  const void* Wmu;   // [100][100]
  const void* bmu;
  const void* Wsig;  // [100][100]
  const void* bsig;
  const void* u;     // [1]
  const void* Wpnf;  // [100][100]
  const void* bpnf;
  const void* noise; // [256][32][100]
  void*       out;   // z | mu | lv, each [32][256][100]
};

// Fence-free grid barrier (r5-proven). Cross-step h data is slot-rotated:
// publishes are sc1 device-scope (write-through to MALL, no L2 allocate),
// reads are plain loads of never-before-touched lines => compulsory miss =>
// always current. No cache maintenance anywhere.
__device__ __forceinline__ void gridbar(){
  __syncthreads();
  if (threadIdx.x == 0){
    unsigned arr = __hip_atomic_fetch_add(&g_bar[0], 1u, __ATOMIC_RELAXED,
                                          __HIP_MEMORY_SCOPE_AGENT);
    unsigned target = arr - (arr % NB_ALL) + NB_ALL;
    while (__hip_atomic_load(&g_bar[0], __ATOMIC_RELAXED,
                             __HIP_MEMORY_SCOPE_AGENT) < target)
      __builtin_amdgcn_s_sleep(2);
  }
  __syncthreads();
  __builtin_amdgcn_sched_barrier(0);
}

// ---------------------------------------------------------------------------
__global__ __launch_bounds__(TPB) void k_recur(P2Args a)
{
  __shared__ __align__(16) char smem[57600];
  const int tid  = threadIdx.x;
  const int wv   = tid >> 6;
  const int lane = tid & 63;
  const int ln   = lane & 15, kg = lane >> 4;

  if (blockIdx.x < NB_MM){
    // ===================== GRU matmul block =====================
    float*          gh   = (float*)smem;                    // [2][32][48] f32
    unsigned short* hout = (unsigned short*)(smem + 12288); // [32][16] bf16
    const int c0  = blockIdx.x * 16;
    const bool act = (wv < 12);
    const int mt = wv & 1, nt = (wv >> 1) % 3, kh = wv / 6;

    bf16x8 bfrag[16];                         // W_hh slice, resident all 256 steps
    if (act){
      const size_t base = (size_t)(nt * 1024 + c0 + ln) * 1024 + kh * 512 + kg * 8;
      for (int ks = 0; ks < 16; ++ks){
        unsigned short tmp[8];
#pragma unroll
        for (int q = 0; q < 8; ++q) tmp[q] = ldbf(a.Whh, base + ks * 32 + q);
        bfrag[ks] = *(bf16x8*)tmp;
      }
    }

    float bhr = 0.f, bhz = 0.f, bhn = 0.f;
    const int eb = tid >> 4, ej = tid & 15;
    if (tid < 512){
      bhr = ldin(a.bhh, c0 + ej);
      bhz = ldin(a.bhh, 1024 + c0 + ej);
      bhn = ldin(a.bhh, 2048 + c0 + ej);
    }
    float h_old = 0.f;

    for (int i = 0; i <= WSTEPS; ++i){
      if (i < WSTEPS){
        float gir = 0.f, giz = 0.f, gin = 0.f;
        if (tid < 512){
          const size_t go = ((size_t)i * 32 + eb) * 3072 + c0 + ej;
          gir = sane(bf2f(g_gi[go]),        1e4f);
          giz = sane(bf2f(g_gi[go + 1024]), 1e4f);
          gin = sane(bf2f(g_gi[go + 2048]), 1e4f);
        }
        if (act){
          f32x4 acc = (f32x4){0.f, 0.f, 0.f, 0.f};
          const unsigned short* ap = g_hs + (size_t)i * 32768      // slot i = h(i)
                                   + (size_t)(mt * 16 + ln) * 1024 + kh * 512 + kg * 8;
#pragma unroll
          for (int ks = 0; ks < 16; ++ks){
            bf16x8 af = *(const bf16x8*)(ap + ks * 32);            // plain cached
            acc = MFMA16(af, bfrag[ks], acc, 0, 0, 0);
          }
          float* g = gh + (size_t)kh * 1536;
#pragma unroll
          for (int r = 0; r < 4; ++r)
            g[(mt * 16 + kg * 4 + r) * 48 + nt * 16 + ln] = acc[r];
        }
        __syncthreads();
        if (tid < 512){
          const float ghr = gh[eb*48 + ej]      + gh[1536 + eb*48 + ej]      + bhr;
          const float ghz = gh[eb*48 + 16 + ej] + gh[1536 + eb*48 + 16 + ej] + bhz;
          const float ghn = gh[eb*48 + 32 + ej] + gh[1536 + eb*48 + 32 + ej] + bhn;
          const float r  = sigm(gir + ghr);
          const float zg = sigm(giz + ghz);
          const float n  = tanhf(gin + r * ghn);
          const float hn = (1.f - zg) * n + zg * h_old;
          h_old = hn;                          // f32 recurrent path (in-register)
          hout[eb * 16 + ej] = f2bf(hn);
        }
        __syncthreads();
        if (tid < 128){                        // 1KB sc1 publish -> slot i+1
          const int r = tid >> 2, q = tid & 3;
          unsigned long long v = *(const unsigned long long*)&hout[r * 16 + q * 4];
          unsigned long long* dst = (unsigned long long*)
              (g_hs + (size_t)(i + 1) * 32768 + (size_t)r * 1024 + c0) + q;
          __hip_atomic_store(dst, v, __ATOMIC_RELAXED, __HIP_MEMORY_SCOPE_AGENT);
        }
      }
      gridbar();
    }
  } else {
    // ===================== tail (head-chain) block =====================
    unsigned short* zbf = (unsigned short*)smem;           // [32][136] bf16
    unsigned short* abf = (unsigned short*)(smem + 8704);  // [32][136] bf16
    char*  scr   = smem + 17408;
    float* dacc0 = (float*)scr;                            // [32][112]
    float* dacc1 = (float*)(scr + 14336);                  // [32][112]
    float* msout = (float*)scr;                            // [32][200]  (reuse)
    float* zpre  = (float*)(scr + 25600);                  // [32][100]
    float* pnfo  = (float*)scr;                            // [32][112]  (reuse)
    float* ldsb  = (float*)(smem + 55808);                 // 400 f32

    for (int idx = tid; idx < 32 * 136; idx += TPB){ zbf[idx] = 0; abf[idx] = 0; }
    if (tid < 400){
      float v;
      if      (tid < 100) v = ldin(a.bd,   tid);
      else if (tid < 200) v = ldin(a.bmu,  tid - 100);
      else if (tid < 300) v = ldin(a.bsig, tid - 200);
      else                v = ldin(a.bpnf, tid - 300);
      ldsb[tid] = v;
    }
    const float uval = ldin(a.u, 0);

    // one-time fragment preloads (guards zero the pads)
    const int nt_h = wv >> 1, khh = wv & 1;
    bf16x8 fH[16], fZ[2], fMS[4], fP[4];
    if (wv < 14){
      const int d = nt_h * 16 + ln;
      for (int ks = 0; ks < 16; ++ks){
        bf16x8 v;
        for (int q = 0; q < 8; ++q){
          const int k = khh * 512 + ks * 32 + kg * 8 + q;
          v[q] = (d < 100) ? (short)ldbf(a.Wd, (size_t)d * 1124 + 100 + k) : (short)0;
        }
        fH[ks] = v;
      }
      for (int q2 = 0; q2 < 2; ++q2){
        bf16x8 v;
        for (int q = 0; q < 8; ++q){
          const int c = (khh * 2 + q2) * 32 + kg * 8 + q;
          v[q] = (d < 100 && c < 100) ? (short)ldbf(a.Wd, (size_t)d * 1124 + c) : (short)0;
        }
        fZ[q2] = v;
      }
      for (int ks = 0; ks < 4; ++ks){
        bf16x8 v;
        for (int q = 0; q < 8; ++q){
          const int k = ks * 32 + kg * 8 + q;
          v[q] = (d < 100 && k < 100) ? (short)ldbf(a.Wpnf, (size_t)d * 100 + k) : (short)0;
        }
        fP[ks] = v;
      }
    }
    if (wv < 13){
      const int s = wv * 16 + ln;
      for (int ks = 0; ks < 4; ++ks){
        bf16x8 v;
        for (int q = 0; q < 8; ++q){
          const int k = ks * 32 + kg * 8 + q;
          short val = 0;
          if (k < 100){
            if (s < 100)      val = (short)ldbf(a.Wmu,  (size_t)s * 100 + k);
            else if (s < 200) val = (short)ldbf(a.Wsig, (size_t)(s - 100) * 100 + k);
          }
          v[q] = val;
        }
        fMS[ks] = v;
      }
    }

    for (int i = 0; i <= WSTEPS; ++i){
      if (i >= 1){
        const int t = i - 1;                   // step being emitted
        for (int idx = tid; idx < 2 * 32 * 112; idx += TPB) dacc0[idx] = 0.f;
        __syncthreads();
        // s2: dense = h(after step t) @ Wdh^T + z(t-1) @ Wdz^T ; h = slot i
        if (wv < 14){
          f32x4 ac0 = (f32x4){0.f,0.f,0.f,0.f}, ac1 = (f32x4){0.f,0.f,0.f,0.f};
          const unsigned short* ap = g_hs + (size_t)i * 32768
                                   + (size_t)ln * 1024 + khh * 512 + kg * 8;
#pragma unroll
          for (int ks = 0; ks < 16; ++ks){
            bf16x8 a0 = *(const bf16x8*)(ap + ks * 32);
            bf16x8 a1 = *(const bf16x8*)(ap + 16 * 1024 + ks * 32);
            ac0 = MFMA16(a0, fH[ks], ac0, 0, 0, 0);
            ac1 = MFMA16(a1, fH[ks], ac1, 0, 0, 0);
          }
#pragma unroll
          for (int q2 = 0; q2 < 2; ++q2){
            const int kz = (khh * 2 + q2) * 32;
            bf16x8 z0 = *(const bf16x8*)&zbf[ln * 136 + kz + kg * 8];
            bf16x8 z1 = *(const bf16x8*)&zbf[(16 + ln) * 136 + kz + kg * 8];
            ac0 = MFMA16(z0, fZ[q2], ac0, 0, 0, 0);
            ac1 = MFMA16(z1, fZ[q2], ac1, 0, 0, 0);
          }
          float* dst = khh ? dacc1 : dacc0;
#pragma unroll
          for (int r = 0; r < 4; ++r){
            dst[(kg * 4 + r) * 112 + nt_h * 16 + ln]      = ac0[r];
            dst[(16 + kg * 4 + r) * 112 + nt_h * 16 + ln] = ac1[r];
          }
        }
        __syncthreads();
        // s3: dense + bd -> bf16 A staging
        if (tid < 800){
#pragma unroll
          for (int q = 0; q < 4; ++q){
            const int e = tid + 800 * q, b = e / 100, d = e - b * 100;
            const float v = sane(dacc0[b * 112 + d] + dacc1[b * 112 + d] + ldsb[d], 1e4f);
            abf[b * 136 + d] = f2bf(v);
          }
        }
        __syncthreads();
        // s4: [mu_raw | sig_raw] = dense @ [Wmu;Wsig]^T
        if (wv < 13){
          f32x4 m0 = (f32x4){0.f,0.f,0.f,0.f}, m1 = (f32x4){0.f,0.f,0.f,0.f};
#pragma unroll
          for (int ks = 0; ks < 4; ++ks){
            bf16x8 a0 = *(const bf16x8*)&abf[ln * 136 + ks * 32 + kg * 8];
            bf16x8 a1 = *(const bf16x8*)&abf[(16 + ln) * 136 + ks * 32 + kg * 8];
            m0 = MFMA16(a0, fMS[ks], m0, 0, 0, 0);
            m1 = MFMA16(a1, fMS[ks], m1, 0, 0, 0);
          }
          const int s = wv * 16 + ln;
          if (s < 200){
#pragma unroll
            for (int r = 0; r < 4; ++r){
              msout[(kg * 4 + r) * 200 + s]      = m0[r];
              msout[(16 + kg * 4 + r) * 200 + s] = m1[r];
            }
          }
        }
        __syncthreads();
        // s5: mu, lv=softplus, z_pre = mu + exp(lv/2)*eps; emit mu/lv
        if (tid < 800){
#pragma unroll
          for (int q = 0; q < 4; ++q){
            const int e = tid + 800 * q, b = e / 100, d = e - b * 100;
            const float mu = sane(msout[b * 200 + d] + ldsb[100 + d], 1e4f);
            float sg = msout[b * 200 + 100 + d] + ldsb[200 + d];
            sg = fminf(fmaxf(sg, -1e4f), 80.f);
            const float lv = fmaxf(sg, 0.f) + log1pf(__expf(-fabsf(sg)));
            const float eps = ldin(a.noise, ((size_t)t * 32 + b) * 100 + d);
            const float zp = sane(mu + __expf(0.5f * lv) * eps, 1e4f);
            const size_t ob = ((size_t)b * 256 + t) * 100 + d;
            stout(a.out, 819200 + ob, mu);
            stout(a.out, 1638400 + ob, lv);
            zpre[b * 100 + d] = zp;
            abf[b * 136 + d] = f2bf(zp);
          }
        }
        __syncthreads();
        // s6: planar flow z_pre @ Wpnf^T
        if (wv < 14){
          const int pm = wv & 1, pn = wv >> 1;
          f32x4 pc = (f32x4){0.f,0.f,0.f,0.f};
#pragma unroll
          for (int ks = 0; ks < 4; ++ks){
            bf16x8 av = *(const bf16x8*)&abf[(pm * 16 + ln) * 136 + ks * 32 + kg * 8];
            pc = MFMA16(av, fP[ks], pc, 0, 0, 0);
          }
#pragma unroll
          for (int r = 0; r < 4; ++r)
            pnfo[(pm * 16 + kg * 4 + r) * 112 + pn * 16 + ln] = pc[r];
        }
        __syncthreads();
        // s7: z = z_pre + u*tanh(pnf + bpnf); emit z; update z carry
        if (tid < 800){
#pragma unroll
          for (int q = 0; q < 4; ++q){
            const int e = tid + 800 * q, b = e / 100, d = e - b * 100;
            const float zp = zpre[b * 100 + d];
            const float pv = sane(pnfo[b * 112 + d] + ldsb[300 + d], 1e4f);
            const float zf = sane(zp + uval * tanhf(pv), 1e4f);
            stout(a.out, ((size_t)b * 256 + t) * 100 + d, zf);
            zbf[b * 136 + d] = f2bf(zf);
          }
        }
      }
      gridbar();
    }
  }
}

// ---------------------------------------------------------------------------
extern "C" void kernel_launch(void* const* d_in, const int* in_sizes, int n_in,
                              void* d_out, int out_size, void* d_ws, size_t ws_size,
                              hipStream_t stream)
{
  const void* x     = d_in[0];
  const void* Wih   = d_in[1];
  const void* Whh   = d_in[2];
  const void* bih   = d_in[3];
  const void* bhh   = d_in[4];
  const void* Wd    = d_in[5];
  const void* bd    = d_in[6];
  const void* Wmu   = d_in[7];
  const void* bmu   = d_in[8];
  const void* Wsig  = d_in[9];
  const void* bsig  = d_in[10];
  const void* u     = d_in[11];
  const void* Wpnf  = d_in[12];
  const void* bpnf  = d_in[13];
  const void* noise = d_in[14];
  (void)d_ws; (void)ws_size;

  k_probe<<<dim3(1), dim3(64), 0, stream>>>(noise);
  k_state_init<<<dim3(65), dim3(256), 0, stream>>>();
  k_gemm_gi<<<dim3(1536), dim3(256), 0, stream>>>(x, Wih, bih);

  P2Args args{Whh, bhh, Wd, bd, Wmu, bmu, Wsig, bsig, u, Wpnf, bpnf, noise, d_out};
  k_recur<<<dim3(NB_ALL), dim3(TPB), 0, stream>>>(args);
}

// Round 9
// 5583.149 us; speedup vs baseline: 1.3163x; 1.3163x over previous
//
#include <hip/hip_runtime.h>
#include <stdint.h>

// ============================================================================
// Qnet: GRU(IN=4096,H=1024) over W=256 steps, B=32, + VAE head (D=Z=100) + PNF
// 4 launches: k_probe / k_state_init / k_gemm_gi / k_recur (persistent 65
// blocks, 1 grid barrier per timestep).
// History:
//   r3 7666us: leader-only release/acquire barrier. 27us/step.
//   r4 10447us: fence-free + PER-ELEMENT sc1 h path. REGRESSED (latency chain).
//   r5 5306us: fence-free + bulk 64KB sc1 gather into LDS. 18us/step. BEST.
//   r6 7349us: slot-rotated plain-cached h loads. REGRESSED: every fragment
//       load = compulsory L2 miss -> MALL round trip, 3x redundancy
//       (192KB/block/step) vs r5's one coalesced 64KB burst. Gather design
//       settled: bulk sc1 -> LDS wins.
//   r7: r5 base + two targeted fixes (UNMEASURED — broker timeouts rounds
//       7-8; identical resubmit for clean A/B vs r5's 5306us):
//       (1) LDS h-tile: stride 2048B + XOR swizzle off^=(row&7)<<4 on BOTH
//           gather-write and fragment-read -> kills the measured 15.06M
//           bank-conflict cycles (8-way on stride-2064).
//       (2) barrier: arrives distributed over 8 cache lines (128B apart,
//           blk&7); detection = lanes 0..7 each poll one line (single vector
//           atomic load) + shfl_xor sum vs target 65*(i+1) (monotonic).
//           Replaces 65 serialized same-line RMWs + single-lane poll.
// ============================================================================

#define MFMA16 __builtin_amdgcn_mfma_f32_16x16x32_bf16

using f32x4  = __attribute__((ext_vector_type(4))) float;
using bf16x8 = __attribute__((ext_vector_type(8))) short;

static constexpr int NB_MM  = 64;
static constexpr int NB_ALL = 65;
static constexpr int TPB    = 1024;
static constexpr int WSTEPS = 256;

// LDS arena (122,944 B): [0,65536) swizzled h tile (32 rows x 2048B).
// matmul blocks: gh at 65536 (12288B), hout at 77824 (1024B).
// tail block: zbf 65536, abf 74240, scr 82944, ldsb 121344 (+1600).
static constexpr int SM_HS    = 65536;
static constexpr int SM_TOTAL = 122944;

// ---- module-global scratch ----
__device__ __align__(256) unsigned short g_gi[8192u * 3072u];   // 50.33 MB bf16
__device__ __align__(256) unsigned short g_hb[2 * 32 * 1024];   // bf16 h ping-pong
__device__ __align__(256) unsigned       g_bar[256];            // 8 lines, 128B apart
__device__ unsigned g_flag;                                     // 1=f32 io, 0=bf16 io

__device__ __forceinline__ float bf2f(unsigned short v){
  unsigned u = ((unsigned)v) << 16;
  return __builtin_bit_cast(float, u);
}
__device__ __forceinline__ unsigned short f2bf(float f){
  unsigned u = __builtin_bit_cast(unsigned, f);
  u += 0x7FFFu + ((u >> 16) & 1u);          // RNE
  return (unsigned short)(u >> 16);
}
__device__ __forceinline__ float ldin(const void* p, size_t i){
  return g_flag ? ((const float*)p)[i] : bf2f(((const unsigned short*)p)[i]);
}
__device__ __forceinline__ unsigned short ldbf(const void* p, size_t i){
  return g_flag ? f2bf(((const float*)p)[i]) : ((const unsigned short*)p)[i];
}
__device__ __forceinline__ void stout(void* p, size_t i, float v){
  if (g_flag) ((float*)p)[i] = v;
  else        ((unsigned short*)p)[i] = f2bf(v);
}
// 16 consecutive elements -> 16 bf16 (two uint4), vectorized in either dtype
__device__ __forceinline__ void ld16(const void* p, size_t idx,
                                     uint4* lo, uint4* hi){
  if (g_flag){
    const float* f = (const float*)p + idx;
    float4 a = *(const float4*)(f);
    float4 b = *(const float4*)(f + 4);
    float4 c = *(const float4*)(f + 8);
    float4 d = *(const float4*)(f + 12);
    unsigned short s[16];
    s[0]=f2bf(a.x); s[1]=f2bf(a.y); s[2]=f2bf(a.z); s[3]=f2bf(a.w);
    s[4]=f2bf(b.x); s[5]=f2bf(b.y); s[6]=f2bf(b.z); s[7]=f2bf(b.w);
    s[8]=f2bf(c.x); s[9]=f2bf(c.y); s[10]=f2bf(c.z); s[11]=f2bf(c.w);
    s[12]=f2bf(d.x); s[13]=f2bf(d.y); s[14]=f2bf(d.z); s[15]=f2bf(d.w);
    *lo = *(uint4*)s; *hi = *(uint4*)(s + 8);
  } else {
    const unsigned short* q = (const unsigned short*)p + idx;
    *lo = *(const uint4*)q; *hi = *(const uint4*)(q + 8);
  }
}
__device__ __forceinline__ float sigm(float x){ return 1.f / (1.f + __expf(-x)); }
__device__ __forceinline__ float sane(float x, float lim){   // tripwire clamp
  return fminf(fmaxf(x, -lim), lim);
}

// ---------------------------------------------------------------------------
__global__ void k_probe(const void* noise){
  if (threadIdx.x == 0 && blockIdx.x == 0){
    const unsigned* w = (const unsigned*)noise;
    unsigned f = 0;
    for (int k = 0; k < 16; ++k)
      if ((w[k] & 0xFFFFu) > 0x3F80u) f = 1u;
    g_flag = f;
  }
}

// zero g_hb (32768 dw) | g_bar (256 dw)
__global__ void k_state_init(){
  int i = blockIdx.x * blockDim.x + threadIdx.x;
  if (i < 32768) ((unsigned*)g_hb)[i] = 0u;
  else if (i < 33024) g_bar[i - 32768] = 0u;
}

// ---------------------------------------------------------------------------
// gi = x @ W_ih^T + b_ih.  M=8192, N=3072, K=4096. 128x128 tile, BK=32.
__global__ __launch_bounds__(256) void k_gemm_gi(
    const void* __restrict__ x,
    const void* __restrict__ Wih,
    const void* __restrict__ bih)
{
  __shared__ unsigned short As[128 * 40];
  __shared__ unsigned short Bs[128 * 40];
  const int tm = blockIdx.x & 63;
  const int tn = blockIdx.x >> 6;
  const int m0 = tm * 128, n0 = tn * 128;
  const int t  = threadIdx.x;
  const int wave = t >> 6, lane = t & 63;
  const int wm = wave & 1, wn = wave >> 1;
  const int ln = lane & 15, kg = lane >> 4;

  const int srow = t >> 1;
  const int skc  = (t & 1) * 16;
  const int m  = m0 + srow;
  const int bb = m & 31, ww = m >> 5;            // x is [B=32][W=256][4096]
  const size_t aoff = ((size_t)(bb * 256 + ww)) * 4096 + skc;
  const size_t boff = ((size_t)(n0 + srow)) * 4096 + skc;
  unsigned short* asl = &As[srow * 40 + skc];
  unsigned short* bsl = &Bs[srow * 40 + skc];

  f32x4 acc[4][4];
#pragma unroll
  for (int i = 0; i < 4; ++i)
#pragma unroll
    for (int j = 0; j < 4; ++j) acc[i][j] = (f32x4){0.f, 0.f, 0.f, 0.f};

  uint4 av, av2, bv, bv2;
  ld16(x,   aoff, &av, &av2);
  ld16(Wih, boff, &bv, &bv2);

  for (int k0 = 0; k0 < 4096; k0 += 32){
    __syncthreads();
    *(uint4*)asl = av;  *(uint4*)(asl + 8) = av2;
    *(uint4*)bsl = bv;  *(uint4*)(bsl + 8) = bv2;
    __syncthreads();
    if (k0 + 32 < 4096){
      ld16(x,   aoff + k0 + 32, &av, &av2);
      ld16(Wih, boff + k0 + 32, &bv, &bv2);
    }
    bf16x8 af[4], bfv[4];
#pragma unroll
    for (int mt = 0; mt < 4; ++mt)
      af[mt] = *(const bf16x8*)&As[(wm * 64 + mt * 16 + ln) * 40 + kg * 8];
#pragma unroll
    for (int nt = 0; nt < 4; ++nt)
      bfv[nt] = *(const bf16x8*)&Bs[(wn * 64 + nt * 16 + ln) * 40 + kg * 8];
#pragma unroll
    for (int mt = 0; mt < 4; ++mt)
#pragma unroll
      for (int nt = 0; nt < 4; ++nt)
        acc[mt][nt] = MFMA16(af[mt], bfv[nt], acc[mt][nt], 0, 0, 0);
  }

#pragma unroll
  for (int nt = 0; nt < 4; ++nt){
    const int gc = n0 + wn * 64 + nt * 16 + ln;
    const float bias = ldin(bih, gc);
#pragma unroll
    for (int mt = 0; mt < 4; ++mt){
      const int rb = m0 + wm * 64 + mt * 16 + kg * 4;
#pragma unroll
      for (int r = 0; r < 4; ++r)
        g_gi[(size_t)(rb + r) * 3072 + gc] = f2bf(acc[mt][nt][r] + bias);
    }
  }
}

// ---------------------------------------------------------------------------
struct P2Args {
  const void* Whh;   // [3072][1024]
  const void* bhh;   // [3072]
  const void* Wd;    // [100][1124]  (cols 0..99 = z, 100..1123 = h)
  const void* bd;
  const void* Wmu;   // [100][100]
  const void* bmu;
  const void* Wsig;  // [100][100]
  const void* bsig;
  const void* u;     // [1]
  const void* Wpnf;  // [100][100]
  const void* bpnf;
  const void* noise; // [256][32][100]
  void*       out;   // z | mu | lv, each [32][256][100]
};

// Fence-free distributed grid barrier (r7).
// Arrive: leader RMW on line (blk&7) -> ~9 serial RMWs per line in parallel
// (was 65 on one line). Detect: lanes 0..7 poll all 8 lines in ONE vector
// atomic load, shfl_xor-sum, compare vs monotonic target 65*(i+1). Sum can
// only reach 65*(k+1) after every block arrived for step k (a block must
// pass barrier k before arriving k+1), and '>=' lets laggards pass. Producer
// ordering: __syncthreads drains vmcnt(0), so all sc1 h-stores are at the
// coherence point before the leader's arrive issues. No cache maintenance.
__device__ __forceinline__ void gridbar(unsigned target){
  __syncthreads();
  if (threadIdx.x < 8){
    if (threadIdx.x == 0)
      __hip_atomic_fetch_add(&g_bar[(blockIdx.x & 7) * 32], 1u,
                             __ATOMIC_RELAXED, __HIP_MEMORY_SCOPE_AGENT);
    for (;;){
      unsigned s = __hip_atomic_load(&g_bar[threadIdx.x * 32],
                                     __ATOMIC_RELAXED, __HIP_MEMORY_SCOPE_AGENT);
      s += __shfl_xor(s, 1);
      s += __shfl_xor(s, 2);
      s += __shfl_xor(s, 4);
      if (s >= target) break;
      __builtin_amdgcn_s_sleep(1);
    }
  }
  __syncthreads();
  __builtin_amdgcn_sched_barrier(0);
}

// swizzled LDS address for the h tile: row-stride 2048B, off ^= (row&7)<<4.
// Applied identically on gather-write and fragment-read -> consistent, and
// 8-lane read phases hit 8 distinct 16B bank groups -> conflict-free b128.
__device__ __forceinline__ char* lds_h(char* hsbase, int row, int off){
  return hsbase + row * 2048 + (off ^ ((row & 7) << 4));
}

// cooperative coherent stage: g_hb slot -> swizzled LDS tile (64KB)
__device__ __forceinline__ void stage_h(char* hsbase, int slot, int tid){
  const unsigned long long* src =
      (const unsigned long long*)(g_hb + (size_t)slot * 32768);
#pragma unroll
  for (int k = 0; k < 8; ++k){
    const int idx = tid + k * TPB;                  // 8B chunk, lane-contiguous
    unsigned long long v = __hip_atomic_load(src + idx, __ATOMIC_RELAXED,
                                             __HIP_MEMORY_SCOPE_AGENT);
    const int row = idx >> 8;                       // 256 chunks per 2048B row
    const int off = (idx & 255) * 8;
    *(unsigned long long*)lds_h(hsbase, row, off) = v;
  }
}

// ---------------------------------------------------------------------------
__global__ __launch_bounds__(TPB) void k_recur(P2Args a)
{
  __shared__ __align__(16) char smem[SM_TOTAL];
  const int tid  = threadIdx.x;
  const int wv   = tid >> 6;
  const int lane = tid & 63;
  const int ln   = lane & 15, kg = lane >> 4;

  if (blockIdx.x < NB_MM){
    // ===================== GRU matmul block =====================
    float*          gh   = (float*)(smem + SM_HS);                  // [2][32][48]
    unsigned short* hout = (unsigned short*)(smem + SM_HS + 12288); // [32][16]
    const int c0  = blockIdx.x * 16;
    const bool act = (wv < 12);
    const int mt = wv & 1, nt = (wv >> 1) % 3, kh = wv / 6;

    bf16x8 bfrag[16];                         // W_hh slice, resident all 256 steps
    if (act){
      const size_t base = (size_t)(nt * 1024 + c0 + ln) * 1024 + kh * 512 + kg * 8;
      for (int ks = 0; ks < 16; ++ks){
        unsigned short tmp[8];
#pragma unroll
        for (int q = 0; q < 8; ++q) tmp[q] = ldbf(a.Whh, base + ks * 32 + q);
        bfrag[ks] = *(bf16x8*)tmp;
      }
    }

    float bhr = 0.f, bhz = 0.f, bhn = 0.f;
    const int eb = tid >> 4, ej = tid & 15;
    if (tid < 512){
      bhr = ldin(a.bhh, c0 + ej);
      bhz = ldin(a.bhh, 1024 + c0 + ej);
      bhn = ldin(a.bhh, 2048 + c0 + ej);
    }
    float h_old = 0.f;

    for (int i = 0; i <= WSTEPS; ++i){
      if (i < WSTEPS){
        float gir = 0.f, giz = 0.f, gin = 0.f;
        if (tid < 512){
          const size_t go = ((size_t)i * 32 + eb) * 3072 + c0 + ej;
          gir = sane(bf2f(g_gi[go]),        1e4f);
          giz = sane(bf2f(g_gi[go + 1024]), 1e4f);
          gin = sane(bf2f(g_gi[go + 2048]), 1e4f);
        }
        stage_h(smem, i & 1, tid);
        __syncthreads();
        if (act){
          f32x4 acc = (f32x4){0.f, 0.f, 0.f, 0.f};
          const int row = mt * 16 + ln;
#pragma unroll
          for (int ks = 0; ks < 16; ++ks){
            bf16x8 af = *(const bf16x8*)lds_h(smem, row,
                              kh * 1024 + kg * 16 + ks * 64);
            acc = MFMA16(af, bfrag[ks], acc, 0, 0, 0);
          }
          float* g = gh + (size_t)kh * 1536;
#pragma unroll
          for (int r = 0; r < 4; ++r)
            g[(mt * 16 + kg * 4 + r) * 48 + nt * 16 + ln] = acc[r];
        }
        __syncthreads();
        if (tid < 512){
          const float ghr = gh[eb*48 + ej]      + gh[1536 + eb*48 + ej]      + bhr;
          const float ghz = gh[eb*48 + 16 + ej] + gh[1536 + eb*48 + 16 + ej] + bhz;
          const float ghn = gh[eb*48 + 32 + ej] + gh[1536 + eb*48 + 32 + ej] + bhn;
          const float r  = sigm(gir + ghr);
          const float zg = sigm(giz + ghz);
          const float n  = tanhf(gin + r * ghn);
          const float hn = (1.f - zg) * n + zg * h_old;
          h_old = hn;                          // f32 recurrent path (in-register)
          hout[eb * 16 + ej] = f2bf(hn);
        }
        __syncthreads();
        if (tid < 128){                        // 1KB wide coherent h publish
          const int r = tid >> 2, q = tid & 3;
          unsigned long long v = *(const unsigned long long*)&hout[r * 16 + q * 4];
          unsigned long long* dst = (unsigned long long*)
              (g_hb + (size_t)((i + 1) & 1) * 32768 + (size_t)r * 1024 + c0) + q;
          __hip_atomic_store(dst, v, __ATOMIC_RELAXED, __HIP_MEMORY_SCOPE_AGENT);
        }
      }
      gridbar((unsigned)(i + 1) * NB_ALL);
    }
  } else {
    // ===================== tail (head-chain) block =====================
    unsigned short* zbf = (unsigned short*)(smem + SM_HS);          // [32][136]
    unsigned short* abf = (unsigned short*)(smem + SM_HS + 8704);   // [32][136]
    char*  scr   = smem + SM_HS + 17408;
    float* dacc0 = (float*)scr;                            // [32][112]
    float* dacc1 = (float*)(scr + 14336);                  // [32][112]
    float* msout = (float*)scr;                            // [32][200]  (reuse)
    float* zpre  = (float*)(scr + 25600);                  // [32][100]
    float* pnfo  = (float*)scr;                            // [32][112]  (reuse)
    float* ldsb  = (float*)(smem + SM_HS + 55808);         // 400 f32

    for (int idx = tid; idx < 32 * 136; idx += TPB){ zbf[idx] = 0; abf[idx] = 0; }
    if (tid < 400){
      float v;
      if      (tid < 100) v = ldin(a.bd,   tid);
      else if (tid < 200) v = ldin(a.bmu,  tid - 100);
      else if (tid < 300) v = ldin(a.bsig, tid - 200);
      else                v = ldin(a.bpnf, tid - 300);
      ldsb[tid] = v;
    }
    const float uval = ldin(a.u, 0);

    // one-time fragment preloads (guards zero the pads)
    const int nt_h = wv >> 1, khh = wv & 1;
    bf16x8 fH[16], fZ[2], fMS[4], fP[4];
    if (wv < 14){
      const int d = nt_h * 16 + ln;
      for (int ks = 0; ks < 16; ++ks){
        bf16x8 v;
        for (int q = 0; q < 8; ++q){
          const int k = khh * 512 + ks * 32 + kg * 8 + q;
          v[q] = (d < 100) ? (short)ldbf(a.Wd, (size_t)d * 1124 + 100 + k) : (short)0;
        }
        fH[ks] = v;
      }
      for (int q2 = 0; q2 < 2; ++q2){
        bf16x8 v;
        for (int q = 0; q < 8; ++q){
          const int c = (khh * 2 + q2) * 32 + kg * 8 + q;
          v[q] = (d < 100 && c < 100) ? (short)ldbf(a.Wd, (size_t)d * 1124 + c) : (short)0;
        }
        fZ[q2] = v;
      }
      for (int ks = 0; ks < 4; ++ks){
        bf16x8 v;
        for (int q = 0; q < 8; ++q){
          const int k = ks * 32 + kg * 8 + q;
          v[q] = (d < 100 && k < 100) ? (short)ldbf(a.Wpnf, (size_t)d * 100 + k) : (short)0;
        }
        fP[ks] = v;
      }
    }
    if (wv < 13){
      const int s = wv * 16 + ln;
      for (int ks = 0; ks < 4; ++ks){
        bf16x8 v;
        for (int q = 0; q < 8; ++q){
          const int k = ks * 32 + kg * 8 + q;
          short val = 0;
          if (k < 100){
            if (s < 100)      val = (short)ldbf(a.Wmu,  (size_t)s * 100 + k);
            else if (s < 200) val = (short)ldbf(a.Wsig, (size_t)(s - 100) * 100 + k);
          }
          v[q] = val;
        }
        fMS[ks] = v;
      }
    }

    for (int i = 0; i <= WSTEPS; ++i){
      if (i >= 1){
        const int t = i - 1;                   // step being emitted
        for (int idx = tid; idx < 2 * 32 * 112; idx += TPB) dacc0[idx] = 0.f;
        stage_h(smem, i & 1, tid);             // h(after step t), bulk coherent
        __syncthreads();
        // s2: dense = h(after step t) @ Wdh^T + z(t-1) @ Wdz^T
        if (wv < 14){
          f32x4 ac0 = (f32x4){0.f,0.f,0.f,0.f}, ac1 = (f32x4){0.f,0.f,0.f,0.f};
#pragma unroll
          for (int ks = 0; ks < 16; ++ks){
            const int off = khh * 1024 + kg * 16 + ks * 64;
            bf16x8 a0 = *(const bf16x8*)lds_h(smem, ln,      off);
            bf16x8 a1 = *(const bf16x8*)lds_h(smem, 16 + ln, off);
            ac0 = MFMA16(a0, fH[ks], ac0, 0, 0, 0);
            ac1 = MFMA16(a1, fH[ks], ac1, 0, 0, 0);
          }
#pragma unroll
          for (int q2 = 0; q2 < 2; ++q2){
            const int kz = (khh * 2 + q2) * 32;
            bf16x8 z0 = *(const bf16x8*)&zbf[ln * 136 + kz + kg * 8];
            bf16x8 z1 = *(const bf16x8*)&zbf[(16 + ln) * 136 + kz + kg * 8];
            ac0 = MFMA16(z0, fZ[q2], ac0, 0, 0, 0);
            ac1 = MFMA16(z1, fZ[q2], ac1, 0, 0, 0);
          }
          float* dst = khh ? dacc1 : dacc0;
#pragma unroll
          for (int r = 0; r < 4; ++r){
            dst[(kg * 4 + r) * 112 + nt_h * 16 + ln]      = ac0[r];
            dst[(16 + kg * 4 + r) * 112 + nt_h * 16 + ln] = ac1[r];
          }
        }
        __syncthreads();
        // s3: dense + bd -> bf16 A staging
        if (tid < 800){
#pragma unroll
          for (int q = 0; q < 4; ++q){
            const int e = tid + 800 * q, b = e / 100, d = e - b * 100;
            const float v = sane(dacc0[b * 112 + d] + dacc1[b * 112 + d] + ldsb[d], 1e4f);
            abf[b * 136 + d] = f2bf(v);
          }
        }
        __syncthreads();
        // s4: [mu_raw | sig_raw] = dense @ [Wmu;Wsig]^T
        if (wv < 13){
          f32x4 m0 = (f32x4){0.f,0.f,0.f,0.f}, m1 = (f32x4){0.f,0.f,0.f,0.f};
#pragma unroll
          for (int ks = 0; ks < 4; ++ks){
            bf16x8 a0 = *(const bf16x8*)&abf[ln * 136 + ks * 32 + kg * 8];
            bf16x8 a1 = *(const bf16x8*)&abf[(16 + ln) * 136 + ks * 32 + kg * 8];
            m0 = MFMA16(a0, fMS[ks], m0, 0, 0, 0);
            m1 = MFMA16(a1, fMS[ks], m1, 0, 0, 0);
          }
          const int s = wv * 16 + ln;
          if (s < 200){
#pragma unroll
            for (int r = 0; r < 4; ++r){
              msout[(kg * 4 + r) * 200 + s]      = m0[r];
              msout[(16 + kg * 4 + r) * 200 + s] = m1[r];
            }
          }
        }
        __syncthreads();
        // s5: mu, lv=softplus, z_pre = mu + exp(lv/2)*eps; emit mu/lv
        if (tid < 800){
#pragma unroll
          for (int q = 0; q < 4; ++q){
            const int e = tid + 800 * q, b = e / 100, d = e - b * 100;
            const float mu = sane(msout[b * 200 + d] + ldsb[100 + d], 1e4f);
            float sg = msout[b * 200 + 100 + d] + ldsb[200 + d];
            sg = fminf(fmaxf(sg, -1e4f), 80.f);
            const float lv = fmaxf(sg, 0.f) + log1pf(__expf(-fabsf(sg)));
            const float eps = ldin(a.noise, ((size_t)t * 32 + b) * 100 + d);
            const float zp = sane(mu + __expf(0.5f * lv) * eps, 1e4f);
            const size_t ob = ((size_t)b * 256 + t) * 100 + d;
            stout(a.out, 819200 + ob, mu);
            stout(a.out, 1638400 + ob, lv);
            zpre[b * 100 + d] = zp;
            abf[b * 136 + d] = f2bf(zp);
          }
        }
        __syncthreads();
        // s6: planar flow z_pre @ Wpnf^T
        if (wv < 14){
          const int pm = wv & 1, pn = wv >> 1;
          f32x4 pc = (f32x4){0.f,0.f,0.f,0.f};
#pragma unroll
          for (int ks = 0; ks < 4; ++ks){
            bf16x8 av = *(const bf16x8*)&abf[(pm * 16 + ln) * 136 + ks * 32 + kg * 8];
            pc = MFMA16(av, fP[ks], pc, 0, 0, 0);
          }
#pragma unroll
          for (int r = 0; r < 4; ++r)
            pnfo[(pm * 16 + kg * 4 + r) * 112 + pn * 16 + ln] = pc[r];
        }
        __syncthreads();
        // s7: z = z_pre + u*tanh(pnf + bpnf); emit z; update z carry
        if (tid < 800){
#pragma unroll
          for (int q = 0; q < 4; ++q){
            const int e = tid + 800 * q, b = e / 100, d = e - b * 100;
            const float zp = zpre[b * 100 + d];
            const float pv = sane(pnfo[b * 112 + d] + ldsb[300 + d], 1e4f);
            const float zf = sane(zp + uval * tanhf(pv), 1e4f);
            stout(a.out, ((size_t)b * 256 + t) * 100 + d, zf);
            zbf[b * 136 + d] = f2bf(zf);
          }
        }
      }
      gridbar((unsigned)(i + 1) * NB_ALL);
    }
  }
}

// ---------------------------------------------------------------------------
extern "C" void kernel_launch(void* const* d_in, const int* in_sizes, int n_in,
                              void* d_out, int out_size, void* d_ws, size_t ws_size,
                              hipStream_t stream)
{
  const void* x     = d_in[0];
  const void* Wih   = d_in[1];
  const void* Whh   = d_in[2];
  const void* bih   = d_in[3];
  const void* bhh   = d_in[4];
  const void* Wd    = d_in[5];
  const void* bd    = d_in[6];
  const void* Wmu   = d_in[7];
  const void* bmu   = d_in[8];
  const void* Wsig  = d_in[9];
  const void* bsig  = d_in[10];
  const void* u     = d_in[11];
  const void* Wpnf  = d_in[12];
  const void* bpnf  = d_in[13];
  const void* noise = d_in[14];
  (void)d_ws; (void)ws_size;

  k_probe<<<dim3(1), dim3(64), 0, stream>>>(noise);
  k_state_init<<<dim3(129), dim3(256), 0, stream>>>();
  k_gemm_gi<<<dim3(1536), dim3(256), 0, stream>>>(x, Wih, bih);

  P2Args args{Whh, bhh, Wd, bd, Wmu, bmu, Wsig, bsig, u, Wpnf, bpnf, noise, d_out};
  k_recur<<<dim3(NB_ALL), dim3(TPB), 0, stream>>>(args);
}

// Round 12
// 4721.469 us; speedup vs baseline: 1.5566x; 1.1825x over previous
//
#include <hip/hip_runtime.h>
#include <stdint.h>

// ============================================================================
// Qnet: GRU(IN=4096,H=1024) over W=256 steps, B=32, + VAE head (D=Z=100) + PNF
// 4 launches: k_probe / k_state_init / k_gemm_gi / k_recur (persistent 65
// blocks, 1 grid barrier per timestep).
// History:
//   r3 7666us: leader-only release/acquire barrier. 27us/step.
//   r4 10447us: fence-free + PER-ELEMENT sc1 h path. REGRESSED (latency).
//   r5 5306us: fence-free + bulk 64KB sc1 gather into LDS. 18us/step. BEST.
//   r6 7349us: slot-rotated plain-cached PER-FRAGMENT reads. REGRESSED
//       (scattered 16B misses, 3x redundancy) — but PROVED the coherence
//       model: sc1-publish -> plain cached read of fresh lines is correct.
//   r7 5583us: swizzle + distributed barrier: REFUTED BOTH. LDS_BANK_CONFLICT
//       identical 1.506e7 with/without swizzle => conflicts aren't the h-tile
//       reads (and are ~2% of cycles — benign). Distributed arrives: neutral
//       to negative. Reverted both.
//   r8: ONE lever — gather path (UNMEASURED: broker timeouts r10/r11;
//       identical resubmit for clean A/B vs r5). Slot-rotated
//       g_hs[257][32][1024] (write-once addresses). Publish: 8B sc1 stores
//       (1KB/block, as r5). stage_h: cooperative PLAIN uint4 loads (4
//       chunks/thread, coalesced). Lines flow MALL -> reader XCD L2 -> L1;
//       ~8 blocks per XCD share the same 64KB in L2 (sc1 loads could never
//       hit). Replaces 65x8192 8B MALL round-trips per step with ~512
//       coalesced line fetches per block, most L2-hits. LDS layout = r5
//       exactly (2064B stride, conflict-free).
// ============================================================================

#define MFMA16 __builtin_amdgcn_mfma_f32_16x16x32_bf16

using f32x4  = __attribute__((ext_vector_type(4))) float;
using bf16x8 = __attribute__((ext_vector_type(8))) short;

static constexpr int NB_MM  = 64;
static constexpr int NB_ALL = 65;
static constexpr int TPB    = 1024;
static constexpr int WSTEPS = 256;

// LDS layout (one static arena, 123,648 B):
//   [0, 66048)        hs: h staging, 32 rows x 1032 (pad 8) bf16
//   matmul blocks:    gh  at 66048 (12,288 B), hout at 78336 (1,024 B)
//   tail block:       zbf at 66048, abf at 74752, scr at 83456, ldsb at 121856
static constexpr int HS_STRIDE = 1032;   // elems; 2064B row = 516 dw = 4-bank
                                         // offset/row -> conflict-free reads
static constexpr int SM_HS    = 66048;
static constexpr int SM_TOTAL = 123648;

// ---- module-global scratch (~67 MB; r6 proved this scale loads/runs) ----
__device__ __align__(256) unsigned short g_gi[8192u * 3072u];     // 50.33 MB
__device__ __align__(256) unsigned short g_hs[257u * 32u * 1024u];// 16.84 MB
__device__ __align__(256) unsigned       g_bar[64];
__device__ unsigned g_flag;                                       // 1=f32 io

__device__ __forceinline__ float bf2f(unsigned short v){
  unsigned u = ((unsigned)v) << 16;
  return __builtin_bit_cast(float, u);
}
__device__ __forceinline__ unsigned short f2bf(float f){
  unsigned u = __builtin_bit_cast(unsigned, f);
  u += 0x7FFFu + ((u >> 16) & 1u);          // RNE
  return (unsigned short)(u >> 16);
}
__device__ __forceinline__ float ldin(const void* p, size_t i){
  return g_flag ? ((const float*)p)[i] : bf2f(((const unsigned short*)p)[i]);
}
__device__ __forceinline__ unsigned short ldbf(const void* p, size_t i){
  return g_flag ? f2bf(((const float*)p)[i]) : ((const unsigned short*)p)[i];
}
__device__ __forceinline__ void stout(void* p, size_t i, float v){
  if (g_flag) ((float*)p)[i] = v;
  else        ((unsigned short*)p)[i] = f2bf(v);
}
// 16 consecutive elements -> 16 bf16 (two uint4), vectorized in either dtype
__device__ __forceinline__ void ld16(const void* p, size_t idx,
                                     uint4* lo, uint4* hi){
  if (g_flag){
    const float* f = (const float*)p + idx;
    float4 a = *(const float4*)(f);
    float4 b = *(const float4*)(f + 4);
    float4 c = *(const float4*)(f + 8);
    float4 d = *(const float4*)(f + 12);
    unsigned short s[16];
    s[0]=f2bf(a.x); s[1]=f2bf(a.y); s[2]=f2bf(a.z); s[3]=f2bf(a.w);
    s[4]=f2bf(b.x); s[5]=f2bf(b.y); s[6]=f2bf(b.z); s[7]=f2bf(b.w);
    s[8]=f2bf(c.x); s[9]=f2bf(c.y); s[10]=f2bf(c.z); s[11]=f2bf(c.w);
    s[12]=f2bf(d.x); s[13]=f2bf(d.y); s[14]=f2bf(d.z); s[15]=f2bf(d.w);
    *lo = *(uint4*)s; *hi = *(uint4*)(s + 8);
  } else {
    const unsigned short* q = (const unsigned short*)p + idx;
    *lo = *(const uint4*)q; *hi = *(const uint4*)(q + 8);
  }
}
__device__ __forceinline__ float sigm(float x){ return 1.f / (1.f + __expf(-x)); }
__device__ __forceinline__ float sane(float x, float lim){   // tripwire clamp
  return fminf(fmaxf(x, -lim), lim);
}

// ---------------------------------------------------------------------------
__global__ void k_probe(const void* noise){
  if (threadIdx.x == 0 && blockIdx.x == 0){
    const unsigned* w = (const unsigned*)noise;
    unsigned f = 0;
    for (int k = 0; k < 16; ++k)
      if ((w[k] & 0xFFFFu) > 0x3F80u) f = 1u;
    g_flag = f;
  }
}

// zero g_hs slot 0 (16384 dw) | g_bar (64 dw)
__global__ void k_state_init(){
  int i = blockIdx.x * blockDim.x + threadIdx.x;
  if (i < 16384) ((unsigned*)g_hs)[i] = 0u;
  else if (i < 16448) g_bar[i - 16384] = 0u;
}

// ---------------------------------------------------------------------------
// gi = x @ W_ih^T + b_ih.  M=8192, N=3072, K=4096. 128x128 tile, BK=32.
__global__ __launch_bounds__(256) void k_gemm_gi(
    const void* __restrict__ x,
    const void* __restrict__ Wih,
    const void* __restrict__ bih)
{
  __shared__ unsigned short As[128 * 40];
  __shared__ unsigned short Bs[128 * 40];
  const int tm = blockIdx.x & 63;
  const int tn = blockIdx.x >> 6;
  const int m0 = tm * 128, n0 = tn * 128;
  const int t  = threadIdx.x;
  const int wave = t >> 6, lane = t & 63;
  const int wm = wave & 1, wn = wave >> 1;
  const int ln = lane & 15, kg = lane >> 4;

  const int srow = t >> 1;
  const int skc  = (t & 1) * 16;
  const int m  = m0 + srow;
  const int bb = m & 31, ww = m >> 5;            // x is [B=32][W=256][4096]
  const size_t aoff = ((size_t)(bb * 256 + ww)) * 4096 + skc;
  const size_t boff = ((size_t)(n0 + srow)) * 4096 + skc;
  unsigned short* asl = &As[srow * 40 + skc];
  unsigned short* bsl = &Bs[srow * 40 + skc];

  f32x4 acc[4][4];
#pragma unroll
  for (int i = 0; i < 4; ++i)
#pragma unroll
    for (int j = 0; j < 4; ++j) acc[i][j] = (f32x4){0.f, 0.f, 0.f, 0.f};

  uint4 av, av2, bv, bv2;
  ld16(x,   aoff, &av, &av2);
  ld16(Wih, boff, &bv, &bv2);

  for (int k0 = 0; k0 < 4096; k0 += 32){
    __syncthreads();
    *(uint4*)asl = av;  *(uint4*)(asl + 8) = av2;
    *(uint4*)bsl = bv;  *(uint4*)(bsl + 8) = bv2;
    __syncthreads();
    if (k0 + 32 < 4096){
      ld16(x,   aoff + k0 + 32, &av, &av2);
      ld16(Wih, boff + k0 + 32, &bv, &bv2);
    }
    bf16x8 af[4], bfv[4];
#pragma unroll
    for (int mt = 0; mt < 4; ++mt)
      af[mt] = *(const bf16x8*)&As[(wm * 64 + mt * 16 + ln) * 40 + kg * 8];
#pragma unroll
    for (int nt = 0; nt < 4; ++nt)
      bfv[nt] = *(const bf16x8*)&Bs[(wn * 64 + nt * 16 + ln) * 40 + kg * 8];
#pragma unroll
    for (int mt = 0; mt < 4; ++mt)
#pragma unroll
      for (int nt = 0; nt < 4; ++nt)
        acc[mt][nt] = MFMA16(af[mt], bfv[nt], acc[mt][nt], 0, 0, 0);
  }

#pragma unroll
  for (int nt = 0; nt < 4; ++nt){
    const int gc = n0 + wn * 64 + nt * 16 + ln;
    const float bias = ldin(bih, gc);
#pragma unroll
    for (int mt = 0; mt < 4; ++mt){
      const int rb = m0 + wm * 64 + mt * 16 + kg * 4;
#pragma unroll
      for (int r = 0; r < 4; ++r)
        g_gi[(size_t)(rb + r) * 3072 + gc] = f2bf(acc[mt][nt][r] + bias);
    }
  }
}

// ---------------------------------------------------------------------------
struct P2Args {
  const void* Whh;   // [3072][1024]
  const void* bhh;   // [3072]
  const void* Wd;    // [100][1124]  (cols 0..99 = z, 100..1123 = h)
  const void* bd;
  const void* Wmu;   // [100][100]
  const void* bmu;
  const void* Wsig;  // [100][100]
  const void* bsig;
  const void* u;     // [1]
  const void* Wpnf;  // [100][100]
  const void* bpnf;
  const void* noise; // [256][32][100]
  void*       out;   // z | mu | lv, each [32][256][100]
};

// Fence-free grid barrier (r5-proven best). Publishes are sc1 device-scope
// (visible at coherence point when vmcnt drains at __syncthreads, before the
// leader's arrive). Reads are plain loads of never-before-touched slot
// addresses => compulsory miss => always current (validated by r6's pass).
// No cache maintenance anywhere.
__device__ __forceinline__ void gridbar(){
  __syncthreads();
  if (threadIdx.x == 0){
    unsigned arr = __hip_atomic_fetch_add(&g_bar[0], 1u, __ATOMIC_RELAXED,
                                          __HIP_MEMORY_SCOPE_AGENT);
    unsigned target = arr - (arr % NB_ALL) + NB_ALL;
    while (__hip_atomic_load(&g_bar[0], __ATOMIC_RELAXED,
                             __HIP_MEMORY_SCOPE_AGENT) < target)
      __builtin_amdgcn_s_sleep(2);
  }
  __syncthreads();
  __builtin_amdgcn_sched_barrier(0);
}

// cooperative PLAIN-cached stage: g_hs slot -> hs LDS (64KB, 4x16B per thread)
// Fully lane-contiguous 16B loads -> 128B line coalescing; blocks sharing an
// XCD hit the same lines in L2.
__device__ __forceinline__ void stage_h(unsigned short* hs, int slot, int tid){
  const uint4* src = (const uint4*)(g_hs + (size_t)slot * 32768);
#pragma unroll
  for (int k = 0; k < 4; ++k){
    const int idx = tid + k * TPB;                  // 16B chunk index
    uint4 v = src[idx];                             // plain cached load
    const int row = idx >> 7;                       // 128 chunks per row
    const int col = (idx & 127) * 8;                // elem offset in row
    *(uint4*)&hs[row * HS_STRIDE + col] = v;        // contiguous b128 write
  }
}

// ---------------------------------------------------------------------------
__global__ __launch_bounds__(TPB) void k_recur(P2Args a)
{
  __shared__ __align__(16) char smem[SM_TOTAL];
  const int tid  = threadIdx.x;
  const int wv   = tid >> 6;
  const int lane = tid & 63;
  const int ln   = lane & 15, kg = lane >> 4;
  unsigned short* hs = (unsigned short*)smem;       // [32][HS_STRIDE] bf16

  if (blockIdx.x < NB_MM){
    // ===================== GRU matmul block =====================
    float*          gh   = (float*)(smem + SM_HS);          // [2][32][48] f32
    unsigned short* hout = (unsigned short*)(smem + SM_HS + 12288); // [32][16]
    const int c0  = blockIdx.x * 16;
    const bool act = (wv < 12);
    const int mt = wv & 1, nt = (wv >> 1) % 3, kh = wv / 6;

    bf16x8 bfrag[16];                         // W_hh slice, resident all 256 steps
    if (act){
      const size_t base = (size_t)(nt * 1024 + c0 + ln) * 1024 + kh * 512 + kg * 8;
      for (int ks = 0; ks < 16; ++ks){
        unsigned short tmp[8];
#pragma unroll
        for (int q = 0; q < 8; ++q) tmp[q] = ldbf(a.Whh, base + ks * 32 + q);
        bfrag[ks] = *(bf16x8*)tmp;
      }
    }

    float bhr = 0.f, bhz = 0.f, bhn = 0.f;
    const int eb = tid >> 4, ej = tid & 15;
    if (tid < 512){
      bhr = ldin(a.bhh, c0 + ej);
      bhz = ldin(a.bhh, 1024 + c0 + ej);
      bhn = ldin(a.bhh, 2048 + c0 + ej);
    }
    float h_old = 0.f;

    for (int i = 0; i <= WSTEPS; ++i){
      if (i < WSTEPS){
        float gir = 0.f, giz = 0.f, gin = 0.f;
        if (tid < 512){
          const size_t go = ((size_t)i * 32 + eb) * 3072 + c0 + ej;
          gir = sane(bf2f(g_gi[go]),        1e4f);
          giz = sane(bf2f(g_gi[go + 1024]), 1e4f);
          gin = sane(bf2f(g_gi[go + 2048]), 1e4f);
        }
        stage_h(hs, i, tid);                  // slot i = h(i), plain cached
        __syncthreads();
        if (act){
          f32x4 acc = (f32x4){0.f, 0.f, 0.f, 0.f};
          const unsigned short* ap = &hs[(mt * 16 + ln) * HS_STRIDE + kh * 512 + kg * 8];
#pragma unroll
          for (int ks = 0; ks < 16; ++ks){
            bf16x8 af = *(const bf16x8*)(ap + ks * 32);
            acc = MFMA16(af, bfrag[ks], acc, 0, 0, 0);
          }
          float* g = gh + (size_t)kh * 1536;
#pragma unroll
          for (int r = 0; r < 4; ++r)
            g[(mt * 16 + kg * 4 + r) * 48 + nt * 16 + ln] = acc[r];
        }
        __syncthreads();
        if (tid < 512){
          const float ghr = gh[eb*48 + ej]      + gh[1536 + eb*48 + ej]      + bhr;
          const float ghz = gh[eb*48 + 16 + ej] + gh[1536 + eb*48 + 16 + ej] + bhz;
          const float ghn = gh[eb*48 + 32 + ej] + gh[1536 + eb*48 + 32 + ej] + bhn;
          const float r  = sigm(gir + ghr);
          const float zg = sigm(giz + ghz);
          const float n  = tanhf(gin + r * ghn);
          const float hn = (1.f - zg) * n + zg * h_old;
          h_old = hn;                          // f32 recurrent path (in-register)
          hout[eb * 16 + ej] = f2bf(hn);
        }
        __syncthreads();
        if (tid < 128){                        // 1KB sc1 publish -> slot i+1
          const int r = tid >> 2, q = tid & 3;
          unsigned long long v = *(const unsigned long long*)&hout[r * 16 + q * 4];
          unsigned long long* dst = (unsigned long long*)
              (g_hs + (size_t)(i + 1) * 32768 + (size_t)r * 1024 + c0) + q;
          __hip_atomic_store(dst, v, __ATOMIC_RELAXED, __HIP_MEMORY_SCOPE_AGENT);
        }
      }
      gridbar();
    }
  } else {
    // ===================== tail (head-chain) block =====================
    unsigned short* zbf = (unsigned short*)(smem + SM_HS);          // [32][136]
    unsigned short* abf = (unsigned short*)(smem + SM_HS + 8704);   // [32][136]
    char*  scr   = smem + SM_HS + 17408;
    float* dacc0 = (float*)scr;                            // [32][112]
    float* dacc1 = (float*)(scr + 14336);                  // [32][112]
    float* msout = (float*)scr;                            // [32][200]  (reuse)
    float* zpre  = (float*)(scr + 25600);                  // [32][100]
    float* pnfo  = (float*)scr;                            // [32][112]  (reuse)
    float* ldsb  = (float*)(smem + SM_HS + 55808);         // 400 f32

    for (int idx = tid; idx < 32 * 136; idx += TPB){ zbf[idx] = 0; abf[idx] = 0; }
    if (tid < 400){
      float v;
      if      (tid < 100) v = ldin(a.bd,   tid);
      else if (tid < 200) v = ldin(a.bmu,  tid - 100);
      else if (tid < 300) v = ldin(a.bsig, tid - 200);
      else                v = ldin(a.bpnf, tid - 300);
      ldsb[tid] = v;
    }
    const float uval = ldin(a.u, 0);

    // one-time fragment preloads (guards zero the pads)
    const int nt_h = wv >> 1, khh = wv & 1;
    bf16x8 fH[16], fZ[2], fMS[4], fP[4];
    if (wv < 14){
      const int d = nt_h * 16 + ln;
      for (int ks = 0; ks < 16; ++ks){
        bf16x8 v;
        for (int q = 0; q < 8; ++q){
          const int k = khh * 512 + ks * 32 + kg * 8 + q;
          v[q] = (d < 100) ? (short)ldbf(a.Wd, (size_t)d * 1124 + 100 + k) : (short)0;
        }
        fH[ks] = v;
      }
      for (int q2 = 0; q2 < 2; ++q2){
        bf16x8 v;
        for (int q = 0; q < 8; ++q){
          const int c = (khh * 2 + q2) * 32 + kg * 8 + q;
          v[q] = (d < 100 && c < 100) ? (short)ldbf(a.Wd, (size_t)d * 1124 + c) : (short)0;
        }
        fZ[q2] = v;
      }
      for (int ks = 0; ks < 4; ++ks){
        bf16x8 v;
        for (int q = 0; q < 8; ++q){
          const int k = ks * 32 + kg * 8 + q;
          v[q] = (d < 100 && k < 100) ? (short)ldbf(a.Wpnf, (size_t)d * 100 + k) : (short)0;
        }
        fP[ks] = v;
      }
    }
    if (wv < 13){
      const int s = wv * 16 + ln;
      for (int ks = 0; ks < 4; ++ks){
        bf16x8 v;
        for (int q = 0; q < 8; ++q){
          const int k = ks * 32 + kg * 8 + q;
          short val = 0;
          if (k < 100){
            if (s < 100)      val = (short)ldbf(a.Wmu,  (size_t)s * 100 + k);
            else if (s < 200) val = (short)ldbf(a.Wsig, (size_t)(s - 100) * 100 + k);
          }
          v[q] = val;
        }
        fMS[ks] = v;
      }
    }

    for (int i = 0; i <= WSTEPS; ++i){
      if (i >= 1){
        const int t = i - 1;                   // step being emitted
        for (int idx = tid; idx < 2 * 32 * 112; idx += TPB) dacc0[idx] = 0.f;
        stage_h(hs, i, tid);                   // slot i = h(after step t)
        __syncthreads();
        // s2: dense = h(after step t) @ Wdh^T + z(t-1) @ Wdz^T
        if (wv < 14){
          f32x4 ac0 = (f32x4){0.f,0.f,0.f,0.f}, ac1 = (f32x4){0.f,0.f,0.f,0.f};
          const unsigned short* ap0 = &hs[ln * HS_STRIDE + khh * 512 + kg * 8];
          const unsigned short* ap1 = &hs[(16 + ln) * HS_STRIDE + khh * 512 + kg * 8];
#pragma unroll
          for (int ks = 0; ks < 16; ++ks){
            bf16x8 a0 = *(const bf16x8*)(ap0 + ks * 32);
            bf16x8 a1 = *(const bf16x8*)(ap1 + ks * 32);
            ac0 = MFMA16(a0, fH[ks], ac0, 0, 0, 0);
            ac1 = MFMA16(a1, fH[ks], ac1, 0, 0, 0);
          }
#pragma unroll
          for (int q2 = 0; q2 < 2; ++q2){
            const int kz = (khh * 2 + q2) * 32;
            bf16x8 z0 = *(const bf16x8*)&zbf[ln * 136 + kz + kg * 8];
            bf16x8 z1 = *(const bf16x8*)&zbf[(16 + ln) * 136 + kz + kg * 8];
            ac0 = MFMA16(z0, fZ[q2], ac0, 0, 0, 0);
            ac1 = MFMA16(z1, fZ[q2], ac1, 0, 0, 0);
          }
          float* dst = khh ? dacc1 : dacc0;
#pragma unroll
          for (int r = 0; r < 4; ++r){
            dst[(kg * 4 + r) * 112 + nt_h * 16 + ln]      = ac0[r];
            dst[(16 + kg * 4 + r) * 112 + nt_h * 16 + ln] = ac1[r];
          }
        }
        __syncthreads();
        // s3: dense + bd -> bf16 A staging
        if (tid < 800){
#pragma unroll
          for (int q = 0; q < 4; ++q){
            const int e = tid + 800 * q, b = e / 100, d = e - b * 100;
            const float v = sane(dacc0[b * 112 + d] + dacc1[b * 112 + d] + ldsb[d], 1e4f);
            abf[b * 136 + d] = f2bf(v);
          }
        }
        __syncthreads();
        // s4: [mu_raw | sig_raw] = dense @ [Wmu;Wsig]^T
        if (wv < 13){
          f32x4 m0 = (f32x4){0.f,0.f,0.f,0.f}, m1 = (f32x4){0.f,0.f,0.f,0.f};
#pragma unroll
          for (int ks = 0; ks < 4; ++ks){
            bf16x8 a0 = *(const bf16x8*)&abf[ln * 136 + ks * 32 + kg * 8];
            bf16x8 a1 = *(const bf16x8*)&abf[(16 + ln) * 136 + ks * 32 + kg * 8];
            m0 = MFMA16(a0, fMS[ks], m0, 0, 0, 0);
            m1 = MFMA16(a1, fMS[ks], m1, 0, 0, 0);
          }
          const int s = wv * 16 + ln;
          if (s < 200){
#pragma unroll
            for (int r = 0; r < 4; ++r){
              msout[(kg * 4 + r) * 200 + s]      = m0[r];
              msout[(16 + kg * 4 + r) * 200 + s] = m1[r];
            }
          }
        }
        __syncthreads();
        // s5: mu, lv=softplus, z_pre = mu + exp(lv/2)*eps; emit mu/lv
        if (tid < 800){
#pragma unroll
          for (int q = 0; q < 4; ++q){
            const int e = tid + 800 * q, b = e / 100, d = e - b * 100;
            const float mu = sane(msout[b * 200 + d] + ldsb[100 + d], 1e4f);
            float sg = msout[b * 200 + 100 + d] + ldsb[200 + d];
            sg = fminf(fmaxf(sg, -1e4f), 80.f);
            const float lv = fmaxf(sg, 0.f) + log1pf(__expf(-fabsf(sg)));
            const float eps = ldin(a.noise, ((size_t)t * 32 + b) * 100 + d);
            const float zp = sane(mu + __expf(0.5f * lv) * eps, 1e4f);
            const size_t ob = ((size_t)b * 256 + t) * 100 + d;
            stout(a.out, 819200 + ob, mu);
            stout(a.out, 1638400 + ob, lv);
            zpre[b * 100 + d] = zp;
            abf[b * 136 + d] = f2bf(zp);
          }
        }
        __syncthreads();
        // s6: planar flow z_pre @ Wpnf^T
        if (wv < 14){
          const int pm = wv & 1, pn = wv >> 1;
          f32x4 pc = (f32x4){0.f,0.f,0.f,0.f};
#pragma unroll
          for (int ks = 0; ks < 4; ++ks){
            bf16x8 av = *(const bf16x8*)&abf[(pm * 16 + ln) * 136 + ks * 32 + kg * 8];
            pc = MFMA16(av, fP[ks], pc, 0, 0, 0);
          }
#pragma unroll
          for (int r = 0; r < 4; ++r)
            pnfo[(pm * 16 + kg * 4 + r) * 112 + pn * 16 + ln] = pc[r];
        }
        __syncthreads();
        // s7: z = z_pre + u*tanh(pnf + bpnf); emit z; update z carry
        if (tid < 800){
#pragma unroll
          for (int q = 0; q < 4; ++q){
            const int e = tid + 800 * q, b = e / 100, d = e - b * 100;
            const float zp = zpre[b * 100 + d];
            const float pv = sane(pnfo[b * 112 + d] + ldsb[300 + d], 1e4f);
            const float zf = sane(zp + uval * tanhf(pv), 1e4f);
            stout(a.out, ((size_t)b * 256 + t) * 100 + d, zf);
            zbf[b * 136 + d] = f2bf(zf);
          }
        }
      }
      gridbar();
    }
  }
}

// ---------------------------------------------------------------------------
extern "C" void kernel_launch(void* const* d_in, const int* in_sizes, int n_in,
                              void* d_out, int out_size, void* d_ws, size_t ws_size,
                              hipStream_t stream)
{
  const void* x     = d_in[0];
  const void* Wih   = d_in[1];
  const void* Whh   = d_in[2];
  const void* bih   = d_in[3];
  const void* bhh   = d_in[4];
  const void* Wd    = d_in[5];
  const void* bd    = d_in[6];
  const void* Wmu   = d_in[7];
  const void* bmu   = d_in[8];
  const void* Wsig  = d_in[9];
  const void* bsig  = d_in[10];
  const void* u     = d_in[11];
  const void* Wpnf  = d_in[12];
  const void* bpnf  = d_in[13];
  const void* noise = d_in[14];
  (void)d_ws; (void)ws_size;

  k_probe<<<dim3(1), dim3(64), 0, stream>>>(noise);
  k_state_init<<<dim3(65), dim3(256), 0, stream>>>();
  k_gemm_gi<<<dim3(1536), dim3(256), 0, stream>>>(x, Wih, bih);

  P2Args args{Whh, bhh, Wd, bd, Wmu, bmu, Wsig, bsig, u, Wpnf, bpnf, noise, d_out};
  k_recur<<<dim3(NB_ALL), dim3(TPB), 0, stream>>>(args);
}